// Round 10
// baseline (619.645 us; speedup 1.0000x reference)
//
#include <hip/hip_runtime.h>
#include <math.h>

// B=4, S=4096, D_MODEL=1024, D_KEY=64
#define NB 4
#define NS 4096
#define DM 1024
#define DK 64

typedef unsigned short ushort_t;
typedef __bf16 bf16_t;
typedef bf16_t bf16x8 __attribute__((ext_vector_type(8)));
typedef float f32x4 __attribute__((ext_vector_type(4)));

#define MFMA(a, b, c) __builtin_amdgcn_mfma_f32_16x16x32_bf16(a, b, c, 0, 0, 0)

union BF8 {
    ushort_t u[8];
    bf16x8 v;
    uint4 q;
};

// round-to-nearest-even f32 -> bf16 bits (store paths)
__device__ __forceinline__ ushort_t f2bf(float f) {
    union { float f; unsigned u; } x; x.f = f;
    unsigned u = x.u;
    u += 0x7fffu + ((u >> 16) & 1u);
    return (ushort_t)(u >> 16);
}

__device__ __forceinline__ bf16x8 ldb8(const ushort_t* p) {
    BF8 t; t.q = *(const uint4*)p; return t.v;
}

// native-converting packs (compiler emits packed cvt instructions)
__device__ __forceinline__ bf16x8 cvt8(float4 a, float4 b) {
    bf16x8 r;
    r[0] = (bf16_t)a.x; r[1] = (bf16_t)a.y; r[2] = (bf16_t)a.z; r[3] = (bf16_t)a.w;
    r[4] = (bf16_t)b.x; r[5] = (bf16_t)b.y; r[6] = (bf16_t)b.z; r[7] = (bf16_t)b.w;
    return r;
}

__device__ __forceinline__ ushort4 cvt4(float4 f) {
    union { bf16_t b[4]; ushort4 u; } x;
    x.b[0] = (bf16_t)f.x; x.b[1] = (bf16_t)f.y;
    x.b[2] = (bf16_t)f.z; x.b[3] = (bf16_t)f.w;
    return x.u;
}

// ---------------------------------------------------------------------------
// Convert W to bf16 in FRAGMENT-LINEAR layout:
//   Wf[y][ks][nt][lane] (16B each) = W[nt*16+c][ks*32+g*8 .. +8]
// ---------------------------------------------------------------------------
__global__ __launch_bounds__(256) void convw_kernel(
    const float* __restrict__ Wq, const float* __restrict__ Wk,
    const float* __restrict__ Wv, ushort_t* __restrict__ Wf)
{
    const int y = blockIdx.y;
    const float* W = (y == 0) ? Wq : (y == 1) ? Wk : Wv;
    const int q = blockIdx.x * 256 + threadIdx.x;   // 0..8191
    const int lane = q & 63, nt = (q >> 6) & 3, ks = q >> 8;
    const int c = lane & 15, g = lane >> 4;
    const int row = nt * 16 + c, col = ks * 32 + g * 8;

    float4 a = *(const float4*)(W + (size_t)row * DM + col);
    float4 b = *(const float4*)(W + (size_t)row * DM + col + 4);
    BF8 t; t.v = cvt8(a, b);
    *(uint4*)(Wf + (size_t)y * 65536 + ((size_t)(ks * 4 + nt) * 64 + lane) * 8) = t.q;
}

// ---------------------------------------------------------------------------
// One 16-row projection strip (the R8 structure): phase A streams 64KB fp32
// front-to-back into XOR-swizzled LDS as bf16; phase B = 16x64 GEMM, K=1024.
// ---------------------------------------------------------------------------
__device__ __forceinline__ void proj_strip(
    int y, int strip, const float* __restrict__ X,
    const ushort_t* __restrict__ Wf, ushort_t* __restrict__ Qp,
    ushort_t* __restrict__ Kp, ushort_t* __restrict__ Vt, char* smem)
{
    const int t = threadIdx.x;
    const float* xs = X + (size_t)(strip * 16) * DM + t * 4;
    float4 f0, f1, f2, f3, f4, f5, f6, f7;

#define LD(F, R) F = *(const float4*)(xs + (size_t)(R) * DM);
#define SK(F, R) { ushort4 o_ = cvt4(F);                                       \
    *(ushort4*)(smem + ((R) * 2048 + ((t * 8) ^ (((R) & 7) << 4)))) = o_; }
#define SB __builtin_amdgcn_sched_barrier(0);

    LD(f0, 0) LD(f1, 1) LD(f2, 2) LD(f3, 3)
    LD(f4, 4) LD(f5, 5) LD(f6, 6) LD(f7, 7) SB
    SK(f0, 0)  LD(f0,  8) SB
    SK(f1, 1)  LD(f1,  9) SB
    SK(f2, 2)  LD(f2, 10) SB
    SK(f3, 3)  LD(f3, 11) SB
    SK(f4, 4)  LD(f4, 12) SB
    SK(f5, 5)  LD(f5, 13) SB
    SK(f6, 6)  LD(f6, 14) SB
    SK(f7, 7)  LD(f7, 15) SB
    SK(f0, 8)  SB
    SK(f1, 9)  SB
    SK(f2, 10) SB
    SK(f3, 11) SB
    SK(f4, 12) SB
    SK(f5, 13) SB
    SK(f6, 14) SB
    SK(f7, 15)
#undef LD
#undef SK
#undef SB

    __syncthreads();

    const int w = t >> 6, lane = t & 63;      // w = n-tile 0..3
    const int c = lane & 15, g = lane >> 4;

    const ushort_t* wfp = Wf + (size_t)y * 65536 + ((size_t)w * 64 + lane) * 8;
    const char* xrow = smem + c * 2048;
    const int xorv = (c & 7) << 4;

    f32x4 acc = (f32x4){0.f, 0.f, 0.f, 0.f};
#pragma unroll 8
    for (int ks = 0; ks < 32; ++ks) {
        const bf16x8 af = *(const bf16x8*)(xrow + ((ks * 64 + g * 16) ^ xorv));
        acc = MFMA(af, ldb8(wfp + (size_t)ks * 2048), acc);
    }

    const int gr0 = strip * 16 + 4 * g;
    const int n = w * 16 + c;
    if (y == 2) {
        const int bb = gr0 >> 12, s0 = gr0 & 4095;
        ushort4 pk;
        pk.x = f2bf(acc[0]); pk.y = f2bf(acc[1]);
        pk.z = f2bf(acc[2]); pk.w = f2bf(acc[3]);
        *(ushort4*)(Vt + (size_t)(bb * 64 + n) * NS + s0) = pk;
    } else {
        ushort_t* Out = (y == 0) ? Qp : Kp;
        const float scl = (y == 0) ? 0.125f : 1.0f;   // 1/sqrt(64) folded into Q
#pragma unroll
        for (int r = 0; r < 4; ++r)
            Out[(size_t)(gr0 + r) * DK + n] = f2bf(acc[r] * scl);
    }
}

// ---------------------------------------------------------------------------
// One causal-attention q-tile (16 rows), the proven R8 body on carved LDS.
// ---------------------------------------------------------------------------
__device__ __forceinline__ void attn_tile(
    int b, int t, const ushort_t* __restrict__ Qp,
    const ushort_t* __restrict__ Kp, const ushort_t* __restrict__ Vt,
    float* __restrict__ O, char* smem)
{
    float* sAcc = (float*)smem;                    // [4][16][64] 16384B
    float* sM   = (float*)(smem + 16384);          // [4][16]       256B
    float* sL   = (float*)(smem + 16640);          // [4][16]       256B
    ushort_t* Pb = (ushort_t*)(smem + 16896);      // [4][16][40]  5120B

    const int tid = threadIdx.x, w = tid >> 6, lane = tid & 63;
    const int c = lane & 15, g = lane >> 4;
    const int q0 = t * 16;

    const ushort_t* qb = Qp + (size_t)(b * NS + q0 + c) * DK + g * 8;
    const bf16x8 aq0 = ldb8(qb);
    const bf16x8 aq1 = ldb8(qb + 32);

    f32x4 acc[4];
#pragma unroll
    for (int i = 0; i < 4; ++i) acc[i] = (f32x4){0.f, 0.f, 0.f, 0.f};
    float m[4] = {-1e30f, -1e30f, -1e30f, -1e30f};
    float lp[4] = {0.f, 0.f, 0.f, 0.f};

    const ushort_t* kb = Kp + (size_t)b * NS * DK;
    const ushort_t* vb = Vt + (size_t)b * DK * NS;
    const int lastj = t >> 1;

    for (int j = w; j <= lastj; j += 4) {
        const int ks0 = j * 32;
        const ushort_t* k0 = kb + (size_t)(ks0 + c) * DK + g * 8;

        f32x4 s0 = (f32x4){0.f, 0.f, 0.f, 0.f};
        f32x4 s1 = (f32x4){0.f, 0.f, 0.f, 0.f};
        s0 = MFMA(aq0, ldb8(k0), s0);
        s0 = MFMA(aq1, ldb8(k0 + 32), s0);
        s1 = MFMA(aq0, ldb8(k0 + 16 * DK), s1);
        s1 = MFMA(aq1, ldb8(k0 + 16 * DK + 32), s1);

        if (j == lastj) {
#pragma unroll
            for (int r = 0; r < 4; ++r) {
                const int q = q0 + 4 * g + r;
                if (ks0 + c > q)      s0[r] = -1e30f;
                if (ks0 + 16 + c > q) s1[r] = -1e30f;
            }
        }

        float p0[4], p1[4];
#pragma unroll
        for (int r = 0; r < 4; ++r) {
            float tm = fmaxf(s0[r], s1[r]);
            tm = fmaxf(tm, __shfl_xor(tm, 1));
            tm = fmaxf(tm, __shfl_xor(tm, 2));
            tm = fmaxf(tm, __shfl_xor(tm, 4));
            tm = fmaxf(tm, __shfl_xor(tm, 8));
            const float mn = fmaxf(m[r], tm);
            const float sc = __expf(m[r] - mn);
            m[r] = mn;
            p0[r] = __expf(s0[r] - mn);
            p1[r] = __expf(s1[r] - mn);
            lp[r] = lp[r] * sc + p0[r] + p1[r];
            acc[0][r] *= sc; acc[1][r] *= sc; acc[2][r] *= sc; acc[3][r] *= sc;
        }

        ushort_t* pr = Pb + (size_t)w * 640 + (4 * g) * 40 + c;
#pragma unroll
        for (int r = 0; r < 4; ++r) {
            pr[r * 40]      = f2bf(p0[r]);
            pr[r * 40 + 16] = f2bf(p1[r]);
        }
        const bf16x8 pa = *(const bf16x8*)(Pb + (size_t)w * 640 + c * 40 + g * 8);

#pragma unroll
        for (int dt = 0; dt < 4; ++dt) {
            bf16x8 vf = ldb8(vb + (size_t)(dt * 16 + c) * NS + ks0 + g * 8);
            acc[dt] = MFMA(pa, vf, acc[dt]);
        }
    }

#pragma unroll
    for (int r = 0; r < 4; ++r) {
        float l = lp[r];
        l += __shfl_xor(l, 1); l += __shfl_xor(l, 2);
        l += __shfl_xor(l, 4); l += __shfl_xor(l, 8);
        lp[r] = l;
    }

#pragma unroll
    for (int dt = 0; dt < 4; ++dt)
#pragma unroll
        for (int r = 0; r < 4; ++r)
            sAcc[(size_t)(w * 16 + 4 * g + r) * 64 + dt * 16 + c] = acc[dt][r];
    if (c == 0) {
#pragma unroll
        for (int r = 0; r < 4; ++r) {
            sM[w * 16 + 4 * g + r] = m[r];
            sL[w * 16 + 4 * g + r] = lp[r];
        }
    }
    __syncthreads();

    const int row = tid >> 4, c4 = (tid & 15) * 4;
    const float m0v = sM[row], m1v = sM[16 + row], m2v = sM[32 + row], m3v = sM[48 + row];
    const float M = fmaxf(fmaxf(m0v, m1v), fmaxf(m2v, m3v));
    const float e0 = __expf(m0v - M), e1 = __expf(m1v - M);
    const float e2 = __expf(m2v - M), e3 = __expf(m3v - M);
    const float L = sL[row] * e0 + sL[16 + row] * e1 + sL[32 + row] * e2 + sL[48 + row] * e3;
    const float inv = 1.f / L;
#define SA(u, i) sAcc[(size_t)((u) * 16 + row) * 64 + c4 + (i)]
    float4 o;
    o.x = (SA(0,0)*e0 + SA(1,0)*e1 + SA(2,0)*e2 + SA(3,0)*e3) * inv;
    o.y = (SA(0,1)*e0 + SA(1,1)*e1 + SA(2,1)*e2 + SA(3,1)*e3) * inv;
    o.z = (SA(0,2)*e0 + SA(1,2)*e1 + SA(2,2)*e2 + SA(3,2)*e3) * inv;
    o.w = (SA(0,3)*e0 + SA(1,3)*e1 + SA(2,3)*e2 + SA(3,3)*e3) * inv;
#undef SA
    *(float4*)(O + (size_t)(b * NS + q0 + row) * DK + c4) = o;
    __syncthreads();   // protect LDS reuse by the next tile
}

// ---------------------------------------------------------------------------
// Fused producer-consumer kernel. 1280 blocks (= 5/CU by 32KB LDS):
//   bid <  1024 : proj worker -- 3 strip-tasks, batch-major order; after each
//                 strip: threadfence + atomicAdd(cnt[batch]) (release).
//   bid >= 1024 : attn worker -- 4 q-tiles (same t, batches 0..3); spins on
//                 cnt[b]==768 (batch fully projected) then runs the tile.
// Deadlock-free: producers never wait and occupy the low block IDs, so even
// under reduced residency the worst case is serialization, not hang.
// ---------------------------------------------------------------------------
__global__ __launch_bounds__(256, 5) void fused_kernel(
    const float* __restrict__ Qin, const float* __restrict__ Kin,
    const float* __restrict__ Vin, const ushort_t* __restrict__ Wf,
    ushort_t* __restrict__ Qp, ushort_t* __restrict__ Kp,
    ushort_t* __restrict__ Vt, int* __restrict__ cnt, float* __restrict__ O)
{
    __shared__ __align__(16) char smem[32768];
    const int bid = blockIdx.x;

    if (bid < 1024) {
        // ---------------- proj producer ----------------
#pragma unroll 1
        for (int r = 0; r < 3; ++r) {
            const int T = bid + r * 1024;          // 0..3071
            const int batch = T / 768;
            const int q = T % 768;
            const int ysel = q % 3;                // 0->K, 1->V, 2->Q
            const int y = (ysel == 0) ? 1 : (ysel == 1) ? 2 : 0;
            const int strip = batch * 256 + q / 3; // global strip in matrix y
            const float* X = (y == 0) ? Qin : (y == 1) ? Kin : Vin;

            proj_strip(y, strip, X, Wf, Qp, Kp, Vt, smem);

            __threadfence();
            __syncthreads();
            if (threadIdx.x == 0) atomicAdd(&cnt[batch], 1);
        }
    } else {
        // ---------------- attn consumer ----------------
        const int w = bid - 1024;                  // 0..255
#pragma unroll 1
        for (int b = 0; b < NB; ++b) {
            if (threadIdx.x == 0) {
                while (atomicAdd(&cnt[b], 0) < 768)
                    __builtin_amdgcn_s_sleep(32);
            }
            __syncthreads();
            __threadfence();
            const int t = (b & 1) ? (255 - w) : w; // heavy/light pairing
            attn_tile(b, t, Qp, Kp, Vt, O, smem);
        }
    }
}

// ---------------------------------------------------------------------------
extern "C" void kernel_launch(void* const* d_in, const int* in_sizes, int n_in,
                              void* d_out, int out_size, void* d_ws,
                              size_t ws_size, hipStream_t stream)
{
    const float* queries = (const float*)d_in[0];
    const float* keys    = (const float*)d_in[1];
    const float* values  = (const float*)d_in[2];
    const float* Wq      = (const float*)d_in[3];
    const float* Wk      = (const float*)d_in[4];
    const float* Wv      = (const float*)d_in[5];
    // d_in[6] = mask: known causal tril, applied analytically.

    const size_t rows = (size_t)NB * NS;           // 16384
    ushort_t* Wf = (ushort_t*)d_ws;                // 3 x 64 x 1024 bf16, frag-linear
    ushort_t* Qp = Wf + (size_t)3 * 65536;         // [16384, 64] bf16 (pre-scaled)
    ushort_t* Kp = Qp + rows * DK;                 // [16384, 64] bf16
    ushort_t* Vt = Kp + rows * DK;                 // [4][64][4096] bf16 (transposed)
    int*      cnt = (int*)(Vt + rows * DK);        // [4] strip-completion counters

    hipMemsetAsync(cnt, 0, 4 * sizeof(int), stream);
    convw_kernel<<<dim3(32, 3), 256, 0, stream>>>(Wq, Wk, Wv, Wf);
    fused_kernel<<<dim3(1280), 256, 0, stream>>>(queries, keys, values, Wf,
                                                 Qp, Kp, Vt, cnt, (float*)d_out);
}

// Round 12
// 107.956 us; speedup vs baseline: 5.7398x; 5.7398x over previous
//
#include <hip/hip_runtime.h>
#include <math.h>

// B=4, S=4096, D_MODEL=1024, D_KEY=64
#define NB 4
#define NS 4096
#define DM 1024
#define DK 64
#define NQT 256          // 16-row query tiles per batch (attention)

typedef unsigned short ushort_t;
typedef __bf16 bf16_t;
typedef bf16_t bf16x8 __attribute__((ext_vector_type(8)));
typedef float f32x4 __attribute__((ext_vector_type(4)));

#define MFMA(a, b, c) __builtin_amdgcn_mfma_f32_16x16x32_bf16(a, b, c, 0, 0, 0)

union BF8 {
    ushort_t u[8];
    bf16x8 v;
    uint4 q;
};

// round-to-nearest-even f32 -> bf16 bits (store paths)
__device__ __forceinline__ ushort_t f2bf(float f) {
    union { float f; unsigned u; } x; x.f = f;
    unsigned u = x.u;
    u += 0x7fffu + ((u >> 16) & 1u);
    return (ushort_t)(u >> 16);
}

__device__ __forceinline__ bf16x8 ldb8(const ushort_t* p) {
    BF8 t; t.q = *(const uint4*)p; return t.v;
}

// native-converting packs (compiler emits packed cvt instructions)
__device__ __forceinline__ bf16x8 cvt8(float4 a, float4 b) {
    bf16x8 r;
    r[0] = (bf16_t)a.x; r[1] = (bf16_t)a.y; r[2] = (bf16_t)a.z; r[3] = (bf16_t)a.w;
    r[4] = (bf16_t)b.x; r[5] = (bf16_t)b.y; r[6] = (bf16_t)b.z; r[7] = (bf16_t)b.w;
    return r;
}

__device__ __forceinline__ ushort4 cvt4(float4 f) {
    union { bf16_t b[4]; ushort4 u; } x;
    x.b[0] = (bf16_t)f.x; x.b[1] = (bf16_t)f.y;
    x.b[2] = (bf16_t)f.z; x.b[3] = (bf16_t)f.w;
    return x.u;
}

// ---------------------------------------------------------------------------
// Convert W to bf16 in FRAGMENT-LINEAR layout:
//   Wf[y][ks][nt][lane(c,g)] (16B each) = W[nt*16+c][ks*32+g*8 .. +8]
// so a proj B-fragment load is one 1KB CONTIGUOUS wave read (8 cachelines,
// the minimum) instead of 16 strided lines.
// ---------------------------------------------------------------------------
__global__ __launch_bounds__(256) void convw_kernel(
    const float* __restrict__ Wq, const float* __restrict__ Wk,
    const float* __restrict__ Wv, ushort_t* __restrict__ Wf)
{
    const int y = blockIdx.y;
    const float* W = (y == 0) ? Wq : (y == 1) ? Wk : Wv;
    const int q = blockIdx.x * 256 + threadIdx.x;   // 0..8191
    const int lane = q & 63, nt = (q >> 6) & 3, ks = q >> 8;
    const int c = lane & 15, g = lane >> 4;
    const int row = nt * 16 + c, col = ks * 32 + g * 8;

    float4 a = *(const float4*)(W + (size_t)row * DM + col);
    float4 b = *(const float4*)(W + (size_t)row * DM + col + 4);
    BF8 t; t.v = cvt8(a, b);
    *(uint4*)(Wf + (size_t)y * 65536 + ((size_t)(ks * 4 + nt) * 64 + lane) * 8) = t.q;
}

// ---------------------------------------------------------------------------
// Projection: block = one 16-row strip (64KB contiguous fp32), 256 thr/4 waves.
// Phase A: stream the strip FRONT-TO-BACK (each step = 4KB contiguous block
// read), cvt to bf16, XOR-swizzled ds_write into Xs[16][1024] (32KB),
// 8-deep named-reg pipeline, sched_barrier-pinned.
// Phase B: full-K GEMM from LDS; A-frags via swizzled ds_read_b128; B-frags
// via CONTIGUOUS 1KB Wf reads. Wave w = n-tile w.
// ---------------------------------------------------------------------------
__global__ __launch_bounds__(256) void proj_kernel(
    const float* __restrict__ Qin, const float* __restrict__ Kin,
    const float* __restrict__ Vin, const ushort_t* __restrict__ Wf,
    ushort_t* __restrict__ Qp, ushort_t* __restrict__ Kp,
    ushort_t* __restrict__ Vt)
{
    __shared__ ushort_t Xs[16][1024];   // 32 KB, column-XOR-swizzled

    const int y = blockIdx.y;
    const float* X = (y == 0) ? Qin : (y == 1) ? Kin : Vin;
    const int strip = blockIdx.x;       // 0..1023 (16-row strips)
    const int t = threadIdx.x;

    // ---- Phase A: sequential stream of 16 rows, 8 loads in flight ----
    const float* xs = X + (size_t)(strip * 16) * DM + t * 4;
    float4 f0, f1, f2, f3, f4, f5, f6, f7;

#define LD(F, R) F = *(const float4*)(xs + (size_t)(R) * DM);
#define SK(F, R) { ushort4 o_ = cvt4(F);                                       \
    *(ushort4*)((char*)&Xs[0][0] +                                             \
        ((R) * 2048 + ((t * 8) ^ (((R) & 7) << 4)))) = o_; }
#define SB __builtin_amdgcn_sched_barrier(0);

    LD(f0, 0) LD(f1, 1) LD(f2, 2) LD(f3, 3)
    LD(f4, 4) LD(f5, 5) LD(f6, 6) LD(f7, 7) SB
    SK(f0, 0)  LD(f0,  8) SB
    SK(f1, 1)  LD(f1,  9) SB
    SK(f2, 2)  LD(f2, 10) SB
    SK(f3, 3)  LD(f3, 11) SB
    SK(f4, 4)  LD(f4, 12) SB
    SK(f5, 5)  LD(f5, 13) SB
    SK(f6, 6)  LD(f6, 14) SB
    SK(f7, 7)  LD(f7, 15) SB
    SK(f0, 8)  SB
    SK(f1, 9)  SB
    SK(f2, 10) SB
    SK(f3, 11) SB
    SK(f4, 12) SB
    SK(f5, 13) SB
    SK(f6, 14) SB
    SK(f7, 15)
#undef LD
#undef SK
#undef SB

    __syncthreads();

    // ---- Phase B: 16x64 GEMM over K=1024 from LDS + fragment-linear Wf ----
    const int w = t >> 6, lane = t & 63;      // w = n-tile 0..3
    const int c = lane & 15, g = lane >> 4;

    const ushort_t* wfp = Wf + (size_t)y * 65536 + ((size_t)w * 64 + lane) * 8;
    const char* xrow = (const char*)&Xs[0][0] + c * 2048;
    const int xorv = (c & 7) << 4;

    f32x4 acc = (f32x4){0.f, 0.f, 0.f, 0.f};
#pragma unroll 8
    for (int ks = 0; ks < 32; ++ks) {
        const bf16x8 af = *(const bf16x8*)(xrow + ((ks * 64 + g * 16) ^ xorv));
        acc = MFMA(af, ldb8(wfp + (size_t)ks * 2048), acc);
    }

    // ---- epilogue ----
    const int gr0 = strip * 16 + 4 * g;       // first of 4 consecutive rows
    const int n = w * 16 + c;
    if (y == 2) {
        const int bb = gr0 >> 12, s0 = gr0 & 4095;
        ushort4 pk;
        pk.x = f2bf(acc[0]); pk.y = f2bf(acc[1]);
        pk.z = f2bf(acc[2]); pk.w = f2bf(acc[3]);
        *(ushort4*)(Vt + (size_t)(bb * 64 + n) * NS + s0) = pk;
    } else {
        ushort_t* Out = (y == 0) ? Qp : Kp;
        const float scl = (y == 0) ? 0.125f : 1.0f;   // 1/sqrt(64) folded into Q
#pragma unroll
        for (int r = 0; r < 4; ++r)
            Out[(size_t)(gr0 + r) * DK + n] = f2bf(acc[r] * scl);
    }
}

// ---------------------------------------------------------------------------
// Causal flash attention, bf16 MFMA. Block = 1 q-tile (16 rows) x 4 waves.
// Waves split key-tiles round-robin (j = w, w+4, ...), private online softmax,
// P transposed through padded per-wave LDS, 4-way merge at the end.
// ---------------------------------------------------------------------------
__global__ __launch_bounds__(256) void attn_kernel(
    const ushort_t* __restrict__ Qp, const ushort_t* __restrict__ Kp,
    const ushort_t* __restrict__ Vt, float* __restrict__ O)
{
    __shared__ float sAcc[4][16][64];
    __shared__ float sM[4][16];
    __shared__ float sL[4][16];
    __shared__ ushort_t Pb[4][16][40];   // 80B row stride: 2-way conflicts only

    const int b = blockIdx.y;
    int t = blockIdx.x;
    if (b & 1) t = (NQT - 1) - t;        // pair heavy+light tiles per CU

    const int tid = threadIdx.x, w = tid >> 6, lane = tid & 63;
    const int c = lane & 15, g = lane >> 4;
    const int q0 = t * 16;

    const ushort_t* qb = Qp + (size_t)(b * NS + q0 + c) * DK + g * 8;
    const bf16x8 aq0 = ldb8(qb);
    const bf16x8 aq1 = ldb8(qb + 32);

    f32x4 acc[4];
#pragma unroll
    for (int i = 0; i < 4; ++i) acc[i] = (f32x4){0.f, 0.f, 0.f, 0.f};
    float m[4] = {-1e30f, -1e30f, -1e30f, -1e30f};
    float lp[4] = {0.f, 0.f, 0.f, 0.f};

    const ushort_t* kb = Kp + (size_t)b * NS * DK;
    const ushort_t* vb = Vt + (size_t)b * DK * NS;
    const int lastj = t >> 1;

    for (int j = w; j <= lastj; j += 4) {
        const int ks0 = j * 32;
        const ushort_t* k0 = kb + (size_t)(ks0 + c) * DK + g * 8;

        f32x4 s0 = (f32x4){0.f, 0.f, 0.f, 0.f};
        f32x4 s1 = (f32x4){0.f, 0.f, 0.f, 0.f};
        s0 = MFMA(aq0, ldb8(k0), s0);
        s0 = MFMA(aq1, ldb8(k0 + 32), s0);
        s1 = MFMA(aq0, ldb8(k0 + 16 * DK), s1);
        s1 = MFMA(aq1, ldb8(k0 + 16 * DK + 32), s1);

        if (j == lastj) {
#pragma unroll
            for (int r = 0; r < 4; ++r) {
                const int q = q0 + 4 * g + r;
                if (ks0 + c > q)      s0[r] = -1e30f;
                if (ks0 + 16 + c > q) s1[r] = -1e30f;
            }
        }

        float p0[4], p1[4];
#pragma unroll
        for (int r = 0; r < 4; ++r) {
            float tm = fmaxf(s0[r], s1[r]);
            tm = fmaxf(tm, __shfl_xor(tm, 1));
            tm = fmaxf(tm, __shfl_xor(tm, 2));
            tm = fmaxf(tm, __shfl_xor(tm, 4));
            tm = fmaxf(tm, __shfl_xor(tm, 8));
            const float mn = fmaxf(m[r], tm);
            const float sc = __expf(m[r] - mn);
            m[r] = mn;
            p0[r] = __expf(s0[r] - mn);
            p1[r] = __expf(s1[r] - mn);
            lp[r] = lp[r] * sc + p0[r] + p1[r];
            acc[0][r] *= sc; acc[1][r] *= sc; acc[2][r] *= sc; acc[3][r] *= sc;
        }

        ushort_t* pr = &Pb[w][0][0] + (4 * g) * 40 + c;
#pragma unroll
        for (int r = 0; r < 4; ++r) {
            pr[r * 40]      = f2bf(p0[r]);
            pr[r * 40 + 16] = f2bf(p1[r]);
        }
        const bf16x8 pa = *(const bf16x8*)(&Pb[w][c][g * 8]);

#pragma unroll
        for (int dt = 0; dt < 4; ++dt) {
            bf16x8 vf = ldb8(vb + (size_t)(dt * 16 + c) * NS + ks0 + g * 8);
            acc[dt] = MFMA(pa, vf, acc[dt]);
        }
    }

#pragma unroll
    for (int r = 0; r < 4; ++r) {
        float l = lp[r];
        l += __shfl_xor(l, 1); l += __shfl_xor(l, 2);
        l += __shfl_xor(l, 4); l += __shfl_xor(l, 8);
        lp[r] = l;
    }

#pragma unroll
    for (int dt = 0; dt < 4; ++dt)
#pragma unroll
        for (int r = 0; r < 4; ++r)
            sAcc[w][4 * g + r][dt * 16 + c] = acc[dt][r];
    if (c == 0) {
#pragma unroll
        for (int r = 0; r < 4; ++r) { sM[w][4 * g + r] = m[r]; sL[w][4 * g + r] = lp[r]; }
    }
    __syncthreads();

    const int row = tid >> 4, c4 = (tid & 15) * 4;
    const float m0v = sM[0][row], m1v = sM[1][row], m2v = sM[2][row], m3v = sM[3][row];
    const float M = fmaxf(fmaxf(m0v, m1v), fmaxf(m2v, m3v));
    const float e0 = __expf(m0v - M), e1 = __expf(m1v - M);
    const float e2 = __expf(m2v - M), e3 = __expf(m3v - M);
    const float L = sL[0][row] * e0 + sL[1][row] * e1 + sL[2][row] * e2 + sL[3][row] * e3;
    const float inv = 1.f / L;
    float4 o;
    o.x = (sAcc[0][row][c4+0]*e0 + sAcc[1][row][c4+0]*e1 + sAcc[2][row][c4+0]*e2 + sAcc[3][row][c4+0]*e3) * inv;
    o.y = (sAcc[0][row][c4+1]*e0 + sAcc[1][row][c4+1]*e1 + sAcc[2][row][c4+1]*e2 + sAcc[3][row][c4+1]*e3) * inv;
    o.z = (sAcc[0][row][c4+2]*e0 + sAcc[1][row][c4+2]*e1 + sAcc[2][row][c4+2]*e2 + sAcc[3][row][c4+2]*e3) * inv;
    o.w = (sAcc[0][row][c4+3]*e0 + sAcc[1][row][c4+3]*e1 + sAcc[2][row][c4+3]*e2 + sAcc[3][row][c4+3]*e3) * inv;
    *(float4*)(O + (size_t)(b * NS + q0 + row) * DK + c4) = o;
}

// ---------------------------------------------------------------------------
extern "C" void kernel_launch(void* const* d_in, const int* in_sizes, int n_in,
                              void* d_out, int out_size, void* d_ws,
                              size_t ws_size, hipStream_t stream)
{
    const float* queries = (const float*)d_in[0];
    const float* keys    = (const float*)d_in[1];
    const float* values  = (const float*)d_in[2];
    const float* Wq      = (const float*)d_in[3];
    const float* Wk      = (const float*)d_in[4];
    const float* Wv      = (const float*)d_in[5];
    // d_in[6] = mask: known causal tril, applied analytically.

    const size_t rows = (size_t)NB * NS;           // 16384
    ushort_t* Wf = (ushort_t*)d_ws;                // 3 x 64 x 1024 bf16, frag-linear
    ushort_t* Qp = Wf + (size_t)3 * 65536;         // [16384, 64] bf16 (pre-scaled)
    ushort_t* Kp = Qp + rows * DK;                 // [16384, 64] bf16
    ushort_t* Vt = Kp + rows * DK;                 // [4][64][4096] bf16 (transposed)

    convw_kernel<<<dim3(32, 3), 256, 0, stream>>>(Wq, Wk, Wv, Wf);
    proj_kernel<<<dim3(1024, 3), 256, 0, stream>>>(queries, keys, values, Wf,
                                                   Qp, Kp, Vt);
    attn_kernel<<<dim3(NQT, NB), 256, 0, stream>>>(Qp, Kp, Vt, (float*)d_out);
}